// Round 9
// baseline (7629.890 us; speedup 1.0000x reference)
//
#include <hip/hip_runtime.h>
#include <hip/hip_bf16.h>

typedef __bf16 bf16x8 __attribute__((ext_vector_type(8)));
typedef float  f32x4  __attribute__((ext_vector_type(4)));

#define LR_C 0.001f
#define VMCNT(n) asm volatile("s_waitcnt vmcnt(" #n ")" ::: "memory")
#define CFENCE() asm volatile("" ::: "memory")

__device__ __forceinline__ float sigf(float x){ return 1.0f/(1.0f + __expf(-x)); }
__device__ __forceinline__ ushort f2bu(float x){ __hip_bfloat16 h = __float2bfloat16(x); return *(ushort*)&h; }
__device__ __forceinline__ float bu2f(ushort u){ __hip_bfloat16 h = *(__hip_bfloat16*)&u; return __bfloat162float(h); }

__device__ __forceinline__ void gload_lds16(const void* g, void* l){
  __builtin_amdgcn_global_load_lds(
      (const __attribute__((address_space(1))) void*)g,
      (__attribute__((address_space(3))) void*)l, 16, 0, 0);
}

// ---------------- prep kernels ----------------

__global__ void k_cvt_bf16(__hip_bfloat16* dst, const float* src, int n){
  int i = blockIdx.x*256 + threadIdx.x;
  if (i < n) dst[i] = __float2bfloat16(src[i]);
}

__global__ void k_cvt_pad(__hip_bfloat16* dst, const float* src, int rows, int cs, int cd){
  int i = blockIdx.x*256 + threadIdx.x;
  if (i >= rows*cd) return;
  int r = i / cd, c = i % cd;
  float v = (c < cs) ? src[r*cs + c] : 0.0f;
  dst[i] = __float2bfloat16(v);
}

// dst[n][j] (n<sc, stride dstride, j>=sr zero) = src[j][n]
__global__ void k_transpose(__hip_bfloat16* dst, const float* src, int sr, int sc, int dstride){
  int i = blockIdx.x*256 + threadIdx.x;
  if (i >= sc*dstride) return;
  int n = i / dstride, j = i % dstride;
  float v = (j < sr) ? src[j*sc + n] : 0.0f;
  dst[i] = __float2bfloat16(v);
}

__global__ void k_init_state(float* sf, __hip_bfloat16* A, const float* s, int n){
  int i = blockIdx.x*256 + threadIdx.x;
  if (i >= n) return;
  float v = s[i];
  sf[i] = v;
  A[i] = __float2bfloat16(sigf(v));
}

// s3: 8192x10 -> s3f (stride 10), A3 (stride 32, cols 10..31 = 0)
__global__ void k_init_s3(float* s3f, __hip_bfloat16* A3, const float* s3){
  int i = blockIdx.x*256 + threadIdx.x;
  if (i >= 8192*32) return;
  int b = i >> 5, c = i & 31;
  if (c < 10){
    float v = s3[b*10 + c];
    s3f[b*10 + c] = v;
    A3[i] = __float2bfloat16(sigf(v));
  } else {
    A3[i] = __float2bfloat16(0.0f);
  }
}

__global__ void k_zero_bf16(__hip_bfloat16* p, int n){
  int i = blockIdx.x*256 + threadIdx.x;
  if (i < n) p[i] = __float2bfloat16(0.0f);
}

__global__ void k_copy_f32(float* dst, const float* src, int n){
  int i = blockIdx.x*256 + threadIdx.x;
  if (i < n) dst[i] = src[i];
}

// ---------------- 128x128 / BK=32 / 8-wave NT GEMM ----------------
// A (shared by all 8 waves) via LDS: ONE cooperative 512-lane global_load_lds
// per K-step, 3-deep rotation (24 KB), source/read XOR-swizzled both sides.
// B (16 private rows per half-wave) DIRECT global->VGPR, 1-step reg prefetch.
// Per-wave vmcnt: iter issues [B(t+1) x2] then [A(t+3) x1].
// Steady: VMCNT(1) (leaves A(t+2)); first iter VMCNT(2); tail VMCNT(0).
// Wave w: rows wr=(w>>2)*64 + m*16, cols wc=(w&3)*32 + n*16, m<4, n<2.

template<int KK>
__device__ __forceinline__ void gemm128(
    const ushort* __restrict__ A, const ushort* __restrict__ B,
    int lda, int ldb, int Nclamp,
    int brow, int bcol, int t, ushort* As, f32x4 (&acc)[4][2])
{
  const int w   = t >> 6;          // 0..7
  const int l   = t & 63;
  const int fr  = l & 15;
  const int ks  = (l >> 4) * 8;
  const int rks = ks ^ ((fr & 3) << 3);
  const int wr  = (w >> 2) * 64;
  const int wc  = (w & 3) * 32;

#pragma unroll
  for (int m=0;m<4;m++){ acc[m][0]=(f32x4){0.f,0.f,0.f,0.f}; acc[m][1]=(f32x4){0.f,0.f,0.f,0.f}; }

  // A staging: 512 threads cover 128 rows x 32 cols; lane-linear LDS dest.
  const int srow = t >> 2;                               // 0..127
  const int scol = ((t & 3) * 8) ^ ((srow & 3) << 3);    // swizzled source col
  const ushort* gA = A + (size_t)(brow + srow) * lda + scol;

  // B direct: two 16-row groups per wave
  int r0 = bcol + wc + fr;       if (r0 > Nclamp-1) r0 = Nclamp-1;
  int r1 = bcol + wc + 16 + fr;  if (r1 > Nclamp-1) r1 = Nclamp-1;
  const ushort* gB0 = B + (size_t)r0 * ldb + ks;
  const ushort* gB1 = B + (size_t)r1 * ldb + ks;

  auto STAGE_A = [&](int buf, int k0){
    gload_lds16(gA + k0, As + buf*4096 + w*512);
  };

  constexpr int nt = KK >> 5;
  STAGE_A(0, 0);                                   // A(0)
  bf16x8 bn0 = *(const bf16x8*)(gB0);              // B(0)
  bf16x8 bn1 = *(const bf16x8*)(gB1);
  if (nt > 1) STAGE_A(1, 32);                      // A(1)
  if (nt > 2) STAGE_A(2, 64);                      // A(2)
  bf16x8 bc0, bc1;

  int cur = 0;
  for (int tk = 0; tk < nt; ++tk){
    const int rem = nt - 1 - tk;
    if (rem >= 2){ if (tk == 0){ VMCNT(2); } else { VMCNT(1); } }
    else { VMCNT(0); }
    __builtin_amdgcn_s_barrier();
    CFENCE();
    bc0 = bn0; bc1 = bn1;
    if (tk + 1 < nt){
      bn0 = *(const bf16x8*)(gB0 + (tk+1)*32);     // B(tk+1) in flight
      bn1 = *(const bf16x8*)(gB1 + (tk+1)*32);
    }
    const ushort* Ab = As + cur*4096;
    bf16x8 af[4];
#pragma unroll
    for (int m=0;m<4;m++) af[m] = *(const bf16x8*)&Ab[(wr + m*16 + fr)*32 + rks];
#pragma unroll
    for (int m=0;m<4;m++){
      acc[m][0] = __builtin_amdgcn_mfma_f32_16x16x32_bf16(af[m], bc0, acc[m][0], 0, 0, 0);
      acc[m][1] = __builtin_amdgcn_mfma_f32_16x16x32_bf16(af[m], bc1, acc[m][1], 0, 0, 0);
    }
    CFENCE();
    __builtin_amdgcn_s_barrier();                  // all waves done with As[cur]
    CFENCE();
    if (tk + 3 < nt) STAGE_A(cur, (tk+3)*32);
    cur = cur + 1; if (cur == 3) cur = 0;
  }
}

// XCD-aware block map: by%8 == lid%8 so all bx-tiles of a row-band share an XCD
__device__ __forceinline__ void blockmap(int lid, int nbx, int& brow, int& bcol){
  int by = (lid & 7) + 8 * ((lid >> 3) / nbx);
  int bx = (lid >> 3) % nbx;
  brow = by * 128; bcol = bx * 128;
}

// ---------------- fused dispatch kernels ----------------
// D1 = { U2 [0,256) | U3 [256,320) | P1 [320,768) }
// D2 = { P3 [0,256) | P2U1 [256,768) }

__global__ __launch_bounds__(512, 4)
void fusedD1(int base,
             const ushort* __restrict__ A1, const ushort* __restrict__ W1b,
             const ushort* __restrict__ inb, ushort* __restrict__ e0, float* p0out,
             const ushort* __restrict__ e1b, const ushort* __restrict__ W2T,
             float* __restrict__ s2f, const ushort* __restrict__ e2b,
             ushort* __restrict__ A2,
             const ushort* __restrict__ W3T, float* __restrict__ s3f,
             ushort* __restrict__ A3)
{
  __shared__ __align__(16) ushort As[3*4096];
  const int bid = blockIdx.x + base;
  const int t = threadIdx.x;
  const int w = t >> 6, l = t & 63;
  const int fr = l & 15, r4 = (l >> 4) * 4;
  const int wr = (w >> 2) * 64, wc = (w & 3) * 32;
  f32x4 acc[4][2];

  if (bid < 256){                      // U2: s2 += LR*(-e2 + sig'(s2)*(e1@W2))
    int brow, bcol; blockmap(bid, 4, brow, bcol);
    gemm128<1024>(e1b, W2T, 1024, 1024, 512, brow, bcol, t, As, acc);
#pragma unroll
    for (int m=0;m<4;m++)
#pragma unroll
      for (int n=0;n<2;n++){
        int col = bcol + wc + n*16 + fr;
#pragma unroll
        for (int j=0;j<4;j++){
          int row = brow + wr + m*16 + r4 + j;
          size_t ix = (size_t)row*512 + col;
          float s = s2f[ix];
          float a = sigf(s);
          float e2 = bu2f(e2b[ix]);
          float sn = s + LR_C*(-e2 + a*(1.0f-a)*acc[m][n][j]);
          s2f[ix] = sn;
          A2[ix] = f2bu(sigf(sn));
        }
      }
  } else if (bid < 320){               // U3: s3 += LR*sig'(s3)*(e2@W3)
    int brow = (bid - 256) * 128;
    gemm128<512>(e2b, W3T, 512, 512, 16, brow, 0, t, As, acc);
#pragma unroll
    for (int m=0;m<4;m++)
#pragma unroll
      for (int n=0;n<2;n++){
        int col = wc + n*16 + fr;
        if (col >= 10) continue;
#pragma unroll
        for (int j=0;j<4;j++){
          int row = brow + wr + m*16 + r4 + j;
          float s = s3f[(size_t)row*10 + col];
          float a = sigf(s);
          float sn = s + LR_C*(a*(1.0f-a)*acc[m][n][j]);
          s3f[(size_t)row*10 + col] = sn;
          A3[(size_t)row*32 + col] = f2bu(sigf(sn));
        }
      }
  } else {                             // P1: e0 = inb - A1@W1b^T
    int brow, bcol; blockmap(bid - 320, 7, brow, bcol);
    gemm128<1024>(A1, W1b, 1024, 1024, 784, brow, bcol, t, As, acc);
#pragma unroll
    for (int m=0;m<4;m++)
#pragma unroll
      for (int n=0;n<2;n++){
        int col = bcol + wc + n*16 + fr;
        if (col >= 784) continue;
#pragma unroll
        for (int j=0;j<4;j++){
          int row = brow + wr + m*16 + r4 + j;
          float p = acc[m][n][j];
          float e = bu2f(inb[(size_t)row*784 + col]) - p;
          e0[(size_t)row*800 + col] = f2bu(e);
          if (p0out) p0out[(size_t)row*784 + col] = p;
        }
      }
  }
}

__global__ __launch_bounds__(512, 4)
void fusedD2(const ushort* __restrict__ A2, const ushort* __restrict__ W2b,
             const ushort* __restrict__ e0, const ushort* __restrict__ W1T,
             float* __restrict__ s1f, ushort* __restrict__ A1,
             ushort* __restrict__ e1b,
             const ushort* __restrict__ A3, const ushort* __restrict__ W3b,
             const float* __restrict__ s2f, ushort* __restrict__ e2b)
{
  __shared__ __align__(16) ushort As[3*4096];
  const int bid = blockIdx.x;
  const int t = threadIdx.x;
  const int w = t >> 6, l = t & 63;
  const int fr = l & 15, r4 = (l >> 4) * 4;
  const int wr = (w >> 2) * 64, wc = (w & 3) * 32;

  if (bid < 256){                      // P3: e2 = s2 - A3@W3b^T
    int brow, bcol; blockmap(bid, 4, brow, bcol);
    f32x4 acc[4][2];
    gemm128<32>(A3, W3b, 32, 32, 512, brow, bcol, t, As, acc);
#pragma unroll
    for (int m=0;m<4;m++)
#pragma unroll
      for (int n=0;n<2;n++){
        int col = bcol + wc + n*16 + fr;
#pragma unroll
        for (int j=0;j<4;j++){
          int row = brow + wr + m*16 + r4 + j;
          size_t ix = (size_t)row*512 + col;
          float e2 = s2f[ix] - acc[m][n][j];
          e2b[ix] = f2bu(e2);
        }
      }
  } else {                             // P2U1 merged; p1 packed to bf16 between gemms
    int brow, bcol; blockmap(bid - 256, 8, brow, bcol);
    f32x4 acc[4][2];
    gemm128<512>(A2, W2b, 512, 512, 1024, brow, bcol, t, As, acc);   // p1
    uint pP[4][2][2];
#pragma unroll
    for (int m=0;m<4;m++)
#pragma unroll
      for (int n=0;n<2;n++){
        pP[m][n][0] = ((uint)f2bu(acc[m][n][1]) << 16) | f2bu(acc[m][n][0]);
        pP[m][n][1] = ((uint)f2bu(acc[m][n][3]) << 16) | f2bu(acc[m][n][2]);
      }
    gemm128<800>(e0, W1T, 800, 800, 1024, brow, bcol, t, As, acc);   // e0@W1
#pragma unroll
    for (int m=0;m<4;m++)
#pragma unroll
      for (int n=0;n<2;n++){
        int col = bcol + wc + n*16 + fr;
#pragma unroll
        for (int j=0;j<4;j++){
          int row = brow + wr + m*16 + r4 + j;
          size_t ix = (size_t)row*1024 + col;
          float p1 = bu2f((ushort)(pP[m][n][j>>1] >> ((j&1)*16)));
          float s  = s1f[ix];
          float e1 = s - p1;
          float a  = sigf(s);
          float sn = s + LR_C*(-e1 + a*(1.0f-a)*acc[m][n][j]);
          s1f[ix] = sn;
          A1[ix]  = f2bu(sigf(sn));
          e1b[ix] = f2bu(e1);
        }
      }
  }
}

// ---------------- host orchestration ----------------

extern "C" void kernel_launch(void* const* d_in, const int* in_sizes, int n_in,
                              void* d_out, int out_size, void* d_ws, size_t ws_size,
                              hipStream_t stream) {
  const float* input = (const float*)d_in[0];
  const float* s1    = (const float*)d_in[1];
  const float* s2    = (const float*)d_in[2];
  const float* s3    = (const float*)d_in[3];
  const float* W1    = (const float*)d_in[4];
  const float* W2    = (const float*)d_in[5];
  const float* W3    = (const float*)d_in[6];
  float* out = (float*)d_out;

  char* ws = (char*)d_ws;
  size_t off = 0;
  auto take = [&](size_t bytes)->char*{
    char* p = ws + off;
    off = (off + bytes + 255) & ~(size_t)255;
    return p;
  };

  float* s1f = (float*)take(8192ull*1024*4);
  float* s2f = (float*)take(8192ull*512*4);
  float* s3f = (float*)take(8192ull*10*4);
  __hip_bfloat16* A1  = (__hip_bfloat16*)take(8192ull*1024*2);
  __hip_bfloat16* A2  = (__hip_bfloat16*)take(8192ull*512*2);
  __hip_bfloat16* A3  = (__hip_bfloat16*)take(8192ull*32*2);
  __hip_bfloat16* e0  = (__hip_bfloat16*)take(8192ull*800*2);
  __hip_bfloat16* e1b = (__hip_bfloat16*)take(8192ull*1024*2);
  __hip_bfloat16* e2b = (__hip_bfloat16*)take(8192ull*512*2);
  __hip_bfloat16* inb = (__hip_bfloat16*)take(8192ull*784*2);
  __hip_bfloat16* W1b = (__hip_bfloat16*)take(784ull*1024*2);
  __hip_bfloat16* W2b = (__hip_bfloat16*)take(1024ull*512*2);
  __hip_bfloat16* W3b = (__hip_bfloat16*)take(512ull*32*2);
  __hip_bfloat16* W1T = (__hip_bfloat16*)take(1024ull*800*2);
  __hip_bfloat16* W2T = (__hip_bfloat16*)take(512ull*1024*2);
  __hip_bfloat16* W3T = (__hip_bfloat16*)take(16ull*512*2);

  auto cdiv = [](int a, int b){ return (a + b - 1) / b; };

  // --- prep (runs every call; d_ws has no persistent state) ---
  k_cvt_bf16 <<<cdiv(8192*784,256),256,0,stream>>>(inb, input, 8192*784);
  k_cvt_bf16 <<<cdiv(784*1024,256),256,0,stream>>>(W1b, W1, 784*1024);
  k_cvt_bf16 <<<cdiv(1024*512,256),256,0,stream>>>(W2b, W2, 1024*512);
  k_cvt_pad  <<<cdiv(512*32,256),256,0,stream>>>(W3b, W3, 512, 10, 32);
  k_transpose<<<cdiv(1024*800,256),256,0,stream>>>(W1T, W1, 784, 1024, 800);
  k_transpose<<<cdiv(512*1024,256),256,0,stream>>>(W2T, W2, 1024, 512, 1024);
  k_zero_bf16<<<cdiv(16*512,256),256,0,stream>>>(W3T, 16*512);
  k_transpose<<<cdiv(10*512,256),256,0,stream>>>(W3T, W3, 512, 10, 512);
  k_init_state<<<cdiv(8192*1024,256),256,0,stream>>>(s1f, A1, s1, 8192*1024);
  k_init_state<<<cdiv(8192*512,256),256,0,stream>>>(s2f, A2, s2, 8192*512);
  k_init_s3  <<<cdiv(8192*32,256),256,0,stream>>>(s3f, A3, s3);
  k_zero_bf16<<<cdiv(8192*800,256),256,0,stream>>>(e0, 8192*800);   // K-pad cols 784..799

  // --- 60 cycles, 2 dispatches each ---
  for (int c = 0; c < 60; ++c){
    float* p0_dst = (c == 59) ? (out + 8192*10) : nullptr;
    if (c == 0){
      // P1 only (segment [320,768))
      fusedD1<<<448, 512, 0, stream>>>(320, (const ushort*)A1, (const ushort*)W1b,
          (const ushort*)inb, (ushort*)e0, p0_dst,
          (const ushort*)e1b, (const ushort*)W2T, s2f, (const ushort*)e2b,
          (ushort*)A2, (const ushort*)W3T, s3f, (ushort*)A3);
    } else {
      fusedD1<<<768, 512, 0, stream>>>(0, (const ushort*)A1, (const ushort*)W1b,
          (const ushort*)inb, (ushort*)e0, p0_dst,
          (const ushort*)e1b, (const ushort*)W2T, s2f, (const ushort*)e2b,
          (ushort*)A2, (const ushort*)W3T, s3f, (ushort*)A3);
    }
    fusedD2<<<768, 512, 0, stream>>>((const ushort*)A2, (const ushort*)W2b,
        (const ushort*)e0, (const ushort*)W1T, s1f, (ushort*)A1, (ushort*)e1b,
        (const ushort*)A3, (const ushort*)W3b, s2f, (ushort*)e2b);
  }
  // trailing U2(59), U3(59): segments [0,320)
  fusedD1<<<320, 512, 0, stream>>>(0, (const ushort*)A1, (const ushort*)W1b,
      (const ushort*)inb, (ushort*)e0, nullptr,
      (const ushort*)e1b, (const ushort*)W2T, s2f, (const ushort*)e2b,
      (ushort*)A2, (const ushort*)W3T, s3f, (ushort*)A3);

  k_copy_f32<<<cdiv(8192*10,256),256,0,stream>>>(out, s3f, 8192*10);
}

// Round 10
// 6970.908 us; speedup vs baseline: 1.0945x; 1.0945x over previous
//
#include <hip/hip_runtime.h>
#include <hip/hip_bf16.h>

typedef __bf16 bf16x8 __attribute__((ext_vector_type(8)));
typedef float  f32x4  __attribute__((ext_vector_type(4)));

#define LR_C 0.001f
#define VMCNT(n) asm volatile("s_waitcnt vmcnt(" #n ")" ::: "memory")
#define CFENCE() asm volatile("" ::: "memory")

__device__ __forceinline__ float sigf(float x){ return 1.0f/(1.0f + __expf(-x)); }
__device__ __forceinline__ ushort f2bu(float x){ __hip_bfloat16 h = __float2bfloat16(x); return *(ushort*)&h; }
__device__ __forceinline__ float bu2f(ushort u){ __hip_bfloat16 h = *(__hip_bfloat16*)&u; return __bfloat162float(h); }

__device__ __forceinline__ void gload_lds16(const void* g, void* l){
  __builtin_amdgcn_global_load_lds(
      (const __attribute__((address_space(1))) void*)g,
      (__attribute__((address_space(3))) void*)l, 16, 0, 0);
}

// ---------------- prep kernels ----------------

__global__ void k_cvt_bf16(__hip_bfloat16* dst, const float* src, int n){
  int i = blockIdx.x*256 + threadIdx.x;
  if (i < n) dst[i] = __float2bfloat16(src[i]);
}

__global__ void k_cvt_pad(__hip_bfloat16* dst, const float* src, int rows, int cs, int cd){
  int i = blockIdx.x*256 + threadIdx.x;
  if (i >= rows*cd) return;
  int r = i / cd, c = i % cd;
  float v = (c < cs) ? src[r*cs + c] : 0.0f;
  dst[i] = __float2bfloat16(v);
}

// dst[n][j] (n<sc, stride dstride, j>=sr zero) = src[j][n]
__global__ void k_transpose(__hip_bfloat16* dst, const float* src, int sr, int sc, int dstride){
  int i = blockIdx.x*256 + threadIdx.x;
  if (i >= sc*dstride) return;
  int n = i / dstride, j = i % dstride;
  float v = (j < sr) ? src[j*sc + n] : 0.0f;
  dst[i] = __float2bfloat16(v);
}

__global__ void k_init_state(float* sf, __hip_bfloat16* A, const float* s, int n){
  int i = blockIdx.x*256 + threadIdx.x;
  if (i >= n) return;
  float v = s[i];
  sf[i] = v;
  A[i] = __float2bfloat16(sigf(v));
}

// s3: 8192x10 -> s3f (stride 10), A3 (stride 32, cols 10..31 = 0)
__global__ void k_init_s3(float* s3f, __hip_bfloat16* A3, const float* s3){
  int i = blockIdx.x*256 + threadIdx.x;
  if (i >= 8192*32) return;
  int b = i >> 5, c = i & 31;
  if (c < 10){
    float v = s3[b*10 + c];
    s3f[b*10 + c] = v;
    A3[i] = __float2bfloat16(sigf(v));
  } else {
    A3[i] = __float2bfloat16(0.0f);
  }
}

__global__ void k_zero_bf16(__hip_bfloat16* p, int n){
  int i = blockIdx.x*256 + threadIdx.x;
  if (i < n) p[i] = __float2bfloat16(0.0f);
}

__global__ void k_copy_f32(float* dst, const float* src, int n){
  int i = blockIdx.x*256 + threadIdx.x;
  if (i < n) dst[i] = src[i];
}

// ---------------- 64x128 / BK=32 / 4-wave NT GEMM, 2-deep pipelined ----
// (r6 core, proven best: 483 cyc/step-CU at residency 6)
// C = A(8192xK) * B(NxK)^T tile at (brow,bcol); Nclamp clamps B staging rows.
// LDS: As [2][64][32], Bs [2][128][32] ushort (24 KB total).
// Wave w owns cols [w*32, w*32+32): frags acc[m 0..3][n 0..1].
// Source col and ds_read col XOR-swizzled by (row&3)<<3 (both-sides).

__device__ __forceinline__ void gemm64(
    const ushort* __restrict__ A, const ushort* __restrict__ B,
    int lda, int ldb, int K, int Nclamp,
    int brow, int bcol, int t, ushort* As, ushort* Bs, f32x4 (&acc)[4][2])
{
  const int w   = t >> 6;
  const int l   = t & 63;
  const int fr  = l & 15;
  const int ks  = (l >> 4) * 8;
  const int rks = ks ^ ((fr & 3) << 3);

#pragma unroll
  for (int m=0;m<4;m++){ acc[m][0]=(f32x4){0.f,0.f,0.f,0.f}; acc[m][1]=(f32x4){0.f,0.f,0.f,0.f}; }

  const int srow = t >> 2;                               // 0..63
  const int scol = ((t & 3) * 8) ^ ((srow & 3) << 3);    // swizzled source col
  const ushort* gA = A + (size_t)(brow + srow) * lda + scol;
  int rb  = bcol + srow;      if (rb  > Nclamp-1) rb  = Nclamp-1;
  int rb2 = bcol + 64 + srow; if (rb2 > Nclamp-1) rb2 = Nclamp-1;
  const ushort* gB  = B + (size_t)rb  * ldb + scol;      // (64+srow)&3 == srow&3
  const ushort* gB2 = B + (size_t)rb2 * ldb + scol;

  auto STAGE = [&](int buf, int k0){
    gload_lds16(gA  + k0, As + buf*2048 + w*512);
    gload_lds16(gB  + k0, Bs + buf*4096 + w*512);
    gload_lds16(gB2 + k0, Bs + buf*4096 + 2048 + w*512);
  };

  const int nt = K >> 5;
  STAGE(0, 0);
  if (nt > 1) STAGE(1, 32);

  int cur = 0;
  for (int tk = 0; tk < nt; ++tk){
    if (tk + 1 < nt) { VMCNT(3); } else { VMCNT(0); }
    __builtin_amdgcn_s_barrier();
    CFENCE();
    const ushort* Ab = As + cur*2048;
    const ushort* Bb = Bs + cur*4096;
    bf16x8 af[4], bfv[2];
#pragma unroll
    for (int m=0;m<4;m++) af[m]  = *(const bf16x8*)&Ab[(m*16 + fr)*32 + rks];
#pragma unroll
    for (int n=0;n<2;n++) bfv[n] = *(const bf16x8*)&Bb[(w*32 + n*16 + fr)*32 + rks];
#pragma unroll
    for (int m=0;m<4;m++)
#pragma unroll
      for (int n=0;n<2;n++)
        acc[m][n] = __builtin_amdgcn_mfma_f32_16x16x32_bf16(af[m], bfv[n], acc[m][n], 0, 0, 0);
    CFENCE();
    __builtin_amdgcn_s_barrier();
    CFENCE();
    if (tk + 2 < nt) STAGE(cur, (tk+2)*32);
    cur ^= 1;
  }
}

// XCD-aware block map: by%8 == lid%8 so all bx-tiles of a row-band share an XCD
__device__ __forceinline__ void blockmap(int lid, int nbx, int& brow, int& bcol){
  int by = (lid & 7) + 8 * ((lid >> 3) / nbx);
  int bx = (lid >> 3) % nbx;
  brow = by * 64; bcol = bx * 128;
}

// ---------------- dispatch kernels (3 per cycle) ----------------
// D1  = { U2(c-1) [0,512) | P1(c) [512,1408) }
// D2a = { P2(c)   [0,1024) | P3(c) [1024,1536) }
// D2b = { U1(c)   [0,1024) | U3(c) [1024,1152) }

__global__ __launch_bounds__(256, 6)
void fusedD1(int base,
             const ushort* __restrict__ A1, const ushort* __restrict__ W1b,
             const ushort* __restrict__ inb, ushort* __restrict__ e0, float* p0out,
             const ushort* __restrict__ e1b, const ushort* __restrict__ W2T,
             float* __restrict__ s2f, const ushort* __restrict__ e2b,
             ushort* __restrict__ A2)
{
  __shared__ __align__(16) ushort As[2*2048];
  __shared__ __align__(16) ushort Bs[2*4096];
  const int bid = blockIdx.x + base;
  const int t = threadIdx.x;
  const int w = t >> 6, l = t & 63;
  const int fr = l & 15, r4 = (l >> 4) * 4;
  f32x4 acc[4][2];

  if (bid < 512){                      // U2: s2 += LR*(-e2 + sig'(s2)*(e1@W2))
    int brow, bcol; blockmap(bid, 4, brow, bcol);
    gemm64(e1b, W2T, 1024, 1024, 1024, 512, brow, bcol, t, As, Bs, acc);
#pragma unroll
    for (int m=0;m<4;m++)
#pragma unroll
      for (int n=0;n<2;n++){
        int col = bcol + w*32 + n*16 + fr;
#pragma unroll
        for (int j=0;j<4;j++){
          int row = brow + m*16 + r4 + j;
          size_t ix = (size_t)row*512 + col;
          float s = s2f[ix];
          float a = sigf(s);
          float e2 = bu2f(e2b[ix]);
          float sn = s + LR_C*(-e2 + a*(1.0f-a)*acc[m][n][j]);
          s2f[ix] = sn;
          A2[ix] = f2bu(sigf(sn));
        }
      }
  } else {                             // P1: e0 = inb - A1@W1b^T
    int brow, bcol; blockmap(bid - 512, 7, brow, bcol);
    gemm64(A1, W1b, 1024, 1024, 1024, 784, brow, bcol, t, As, Bs, acc);
#pragma unroll
    for (int m=0;m<4;m++)
#pragma unroll
      for (int n=0;n<2;n++){
        int col = bcol + w*32 + n*16 + fr;
        if (col >= 784) continue;
#pragma unroll
        for (int j=0;j<4;j++){
          int row = brow + m*16 + r4 + j;
          float p = acc[m][n][j];
          float e = bu2f(inb[(size_t)row*784 + col]) - p;
          e0[(size_t)row*800 + col] = f2bu(e);
          if (p0out) p0out[(size_t)row*784 + col] = p;
        }
      }
  }
}

__global__ __launch_bounds__(256, 6)
void fusedD2a(const ushort* __restrict__ A2, const ushort* __restrict__ W2b,
              ushort* __restrict__ p1b,
              const ushort* __restrict__ A3, const ushort* __restrict__ W3b,
              const float* __restrict__ s2f, ushort* __restrict__ e2b)
{
  __shared__ __align__(16) ushort As[2*2048];
  __shared__ __align__(16) ushort Bs[2*4096];
  const int bid = blockIdx.x;
  const int t = threadIdx.x;
  const int w = t >> 6, l = t & 63;
  const int fr = l & 15, r4 = (l >> 4) * 4;
  f32x4 acc[4][2];

  if (bid < 1024){                     // P2: p1 = A2@W2b^T  (bf16 out)
    int brow, bcol; blockmap(bid, 8, brow, bcol);
    gemm64(A2, W2b, 512, 512, 512, 1024, brow, bcol, t, As, Bs, acc);
#pragma unroll
    for (int m=0;m<4;m++)
#pragma unroll
      for (int n=0;n<2;n++){
        int col = bcol + w*32 + n*16 + fr;
#pragma unroll
        for (int j=0;j<4;j++){
          int row = brow + m*16 + r4 + j;
          p1b[(size_t)row*1024 + col] = f2bu(acc[m][n][j]);
        }
      }
  } else {                             // P3: e2 = s2 - A3@W3b^T
    int brow, bcol; blockmap(bid - 1024, 4, brow, bcol);
    gemm64(A3, W3b, 32, 32, 32, 512, brow, bcol, t, As, Bs, acc);
#pragma unroll
    for (int m=0;m<4;m++)
#pragma unroll
      for (int n=0;n<2;n++){
        int col = bcol + w*32 + n*16 + fr;
#pragma unroll
        for (int j=0;j<4;j++){
          int row = brow + m*16 + r4 + j;
          size_t ix = (size_t)row*512 + col;
          float e2 = s2f[ix] - acc[m][n][j];
          e2b[ix] = f2bu(e2);
        }
      }
  }
}

__global__ __launch_bounds__(256, 6)
void fusedD2b(const ushort* __restrict__ e0, const ushort* __restrict__ W1T,
              const ushort* __restrict__ p1b,
              float* __restrict__ s1f, ushort* __restrict__ A1,
              ushort* __restrict__ e1b,
              const ushort* __restrict__ e2b, const ushort* __restrict__ W3T,
              float* __restrict__ s3f, ushort* __restrict__ A3)
{
  __shared__ __align__(16) ushort As[2*2048];
  __shared__ __align__(16) ushort Bs[2*4096];
  const int bid = blockIdx.x;
  const int t = threadIdx.x;
  const int w = t >> 6, l = t & 63;
  const int fr = l & 15, r4 = (l >> 4) * 4;
  f32x4 acc[4][2];

  if (bid < 1024){                     // U1: s1 += LR*(-(s1-p1) + sig'(s1)*(e0@W1))
    int brow, bcol; blockmap(bid, 8, brow, bcol);
    gemm64(e0, W1T, 800, 800, 800, 1024, brow, bcol, t, As, Bs, acc);
#pragma unroll
    for (int m=0;m<4;m++)
#pragma unroll
      for (int n=0;n<2;n++){
        int col = bcol + w*32 + n*16 + fr;
#pragma unroll
        for (int j=0;j<4;j++){
          int row = brow + m*16 + r4 + j;
          size_t ix = (size_t)row*1024 + col;
          float p1 = bu2f(p1b[ix]);
          float s  = s1f[ix];
          float e1 = s - p1;
          float a  = sigf(s);
          float sn = s + LR_C*(-e1 + a*(1.0f-a)*acc[m][n][j]);
          s1f[ix] = sn;
          A1[ix]  = f2bu(sigf(sn));
          e1b[ix] = f2bu(e1);
        }
      }
  } else {                             // U3: s3 += LR*sig'(s3)*(e2@W3)
    int brow = (bid - 1024) * 64;
    gemm64(e2b, W3T, 512, 512, 512, 16, brow, 0, t, As, Bs, acc);
#pragma unroll
    for (int m=0;m<4;m++)
#pragma unroll
      for (int n=0;n<2;n++){
        int col = w*32 + n*16 + fr;
        if (col >= 10) continue;
#pragma unroll
        for (int j=0;j<4;j++){
          int row = brow + m*16 + r4 + j;
          float s = s3f[(size_t)row*10 + col];
          float a = sigf(s);
          float sn = s + LR_C*(a*(1.0f-a)*acc[m][n][j]);
          s3f[(size_t)row*10 + col] = sn;
          A3[(size_t)row*32 + col] = f2bu(sigf(sn));
        }
      }
  }
}

// ---------------- host orchestration ----------------

extern "C" void kernel_launch(void* const* d_in, const int* in_sizes, int n_in,
                              void* d_out, int out_size, void* d_ws, size_t ws_size,
                              hipStream_t stream) {
  const float* input = (const float*)d_in[0];
  const float* s1    = (const float*)d_in[1];
  const float* s2    = (const float*)d_in[2];
  const float* s3    = (const float*)d_in[3];
  const float* W1    = (const float*)d_in[4];
  const float* W2    = (const float*)d_in[5];
  const float* W3    = (const float*)d_in[6];
  float* out = (float*)d_out;

  char* ws = (char*)d_ws;
  size_t off = 0;
  auto take = [&](size_t bytes)->char*{
    char* p = ws + off;
    off = (off + bytes + 255) & ~(size_t)255;
    return p;
  };

  float* s1f = (float*)take(8192ull*1024*4);
  float* s2f = (float*)take(8192ull*512*4);
  float* s3f = (float*)take(8192ull*10*4);
  __hip_bfloat16* A1  = (__hip_bfloat16*)take(8192ull*1024*2);
  __hip_bfloat16* A2  = (__hip_bfloat16*)take(8192ull*512*2);
  __hip_bfloat16* A3  = (__hip_bfloat16*)take(8192ull*32*2);
  __hip_bfloat16* e0  = (__hip_bfloat16*)take(8192ull*800*2);
  __hip_bfloat16* e1b = (__hip_bfloat16*)take(8192ull*1024*2);
  __hip_bfloat16* e2b = (__hip_bfloat16*)take(8192ull*512*2);
  __hip_bfloat16* p1b = (__hip_bfloat16*)take(8192ull*1024*2);
  __hip_bfloat16* inb = (__hip_bfloat16*)take(8192ull*784*2);
  __hip_bfloat16* W1b = (__hip_bfloat16*)take(784ull*1024*2);
  __hip_bfloat16* W2b = (__hip_bfloat16*)take(1024ull*512*2);
  __hip_bfloat16* W3b = (__hip_bfloat16*)take(512ull*32*2);
  __hip_bfloat16* W1T = (__hip_bfloat16*)take(1024ull*800*2);
  __hip_bfloat16* W2T = (__hip_bfloat16*)take(512ull*1024*2);
  __hip_bfloat16* W3T = (__hip_bfloat16*)take(16ull*512*2);

  auto cdiv = [](int a, int b){ return (a + b - 1) / b; };

  // --- prep (runs every call; d_ws has no persistent state) ---
  k_cvt_bf16 <<<cdiv(8192*784,256),256,0,stream>>>(inb, input, 8192*784);
  k_cvt_bf16 <<<cdiv(784*1024,256),256,0,stream>>>(W1b, W1, 784*1024);
  k_cvt_bf16 <<<cdiv(1024*512,256),256,0,stream>>>(W2b, W2, 1024*512);
  k_cvt_pad  <<<cdiv(512*32,256),256,0,stream>>>(W3b, W3, 512, 10, 32);
  k_transpose<<<cdiv(1024*800,256),256,0,stream>>>(W1T, W1, 784, 1024, 800);
  k_transpose<<<cdiv(512*1024,256),256,0,stream>>>(W2T, W2, 1024, 512, 1024);
  k_zero_bf16<<<cdiv(16*512,256),256,0,stream>>>(W3T, 16*512);
  k_transpose<<<cdiv(10*512,256),256,0,stream>>>(W3T, W3, 512, 10, 512);
  k_init_state<<<cdiv(8192*1024,256),256,0,stream>>>(s1f, A1, s1, 8192*1024);
  k_init_state<<<cdiv(8192*512,256),256,0,stream>>>(s2f, A2, s2, 8192*512);
  k_init_s3  <<<cdiv(8192*32,256),256,0,stream>>>(s3f, A3, s3);
  k_zero_bf16<<<cdiv(8192*800,256),256,0,stream>>>(e0, 8192*800);   // K-pad cols 784..799

  // --- 60 cycles, 3 dispatches each ---
  for (int c = 0; c < 60; ++c){
    float* p0_dst = (c == 59) ? (out + 8192*10) : nullptr;
    if (c == 0){
      // P1 only (segment [512,1408))
      fusedD1<<<896, 256, 0, stream>>>(512, (const ushort*)A1, (const ushort*)W1b,
          (const ushort*)inb, (ushort*)e0, p0_dst,
          (const ushort*)e1b, (const ushort*)W2T, s2f, (const ushort*)e2b,
          (ushort*)A2);
    } else {
      fusedD1<<<1408, 256, 0, stream>>>(0, (const ushort*)A1, (const ushort*)W1b,
          (const ushort*)inb, (ushort*)e0, p0_dst,
          (const ushort*)e1b, (const ushort*)W2T, s2f, (const ushort*)e2b,
          (ushort*)A2);
    }
    fusedD2a<<<1536, 256, 0, stream>>>((const ushort*)A2, (const ushort*)W2b,
        (ushort*)p1b,
        (const ushort*)A3, (const ushort*)W3b, s2f, (ushort*)e2b);
    fusedD2b<<<1152, 256, 0, stream>>>((const ushort*)e0, (const ushort*)W1T,
        (const ushort*)p1b, s1f, (ushort*)A1, (ushort*)e1b,
        (const ushort*)e2b, (const ushort*)W3T, s3f, (ushort*)A3);
  }
  // trailing U2(59): segment [0,512)
  fusedD1<<<512, 256, 0, stream>>>(0, (const ushort*)A1, (const ushort*)W1b,
      (const ushort*)inb, (ushort*)e0, nullptr,
      (const ushort*)e1b, (const ushort*)W2T, s2f, (const ushort*)e2b,
      (ushort*)A2);

  k_copy_f32<<<cdiv(8192*10,256),256,0,stream>>>(out, s3f, 8192*10);
}